// Round 18
// baseline (280.649 us; speedup 1.0000x reference)
//
#include <hip/hip_runtime.h>
#include <hip/hip_bf16.h>
#include <stdint.h>
#include <math.h>

#define DEV static __device__ __forceinline__

typedef __attribute__((ext_vector_type(8))) short bf16x8;
typedef __attribute__((ext_vector_type(4))) float f32x4;
typedef unsigned int u32;

static constexpr int T = 4096;
static constexpr int BATCH = 8;
static constexpr int DM = 1024;            // d_model
static constexpr int M1 = BATCH * T;       // 32768 rows into GEMM1
static constexpr int M2 = BATCH * (T + 1); // 32776 rows into GEMM2
static constexpr int M2P = 129 * 256;      // 33024 padded rows for S (256-row tiles)
static constexpr int NCH = 64;
static constexpr int CL = T / NCH;
static constexpr int NT = 32;              // K tiles (BK=32, K=1024)

DEV unsigned short f2bf(float f) {
  union { float f; unsigned u; } v; v.f = f;
  unsigned u = v.u;
  return (unsigned short)((u + 0x7fffu + ((u >> 16) & 1u)) >> 16);
}
DEV float bf2f(unsigned short s) {
  union { unsigned u; float f; } v; v.u = ((unsigned)s) << 16;
  return v.f;
}

// async global->LDS, 16B per lane. lds dest wave-uniform; g per-lane.
DEV void gl_lds16(const unsigned short* g, unsigned short* lds) {
  __builtin_amdgcn_global_load_lds(
      (const __attribute__((address_space(1))) u32*)g,
      (__attribute__((address_space(3))) u32*)lds,
      16, 0, 0);
}

// ---------------- fp32 -> bf16 convert of inputs ----------------
__global__ void k_cvt_x(const float4* __restrict__ x, ushort4* __restrict__ o) {
  int i = blockIdx.x * 256 + threadIdx.x;
  float4 v = x[i];
  ushort4 r;
  r.x = f2bf(v.x); r.y = f2bf(v.y); r.z = f2bf(v.z); r.w = f2bf(v.w);
  o[i] = r;
}

// ------------- transpose + convert weights: Wt[n][k] = W[k][n] -------------
__global__ void k_transpose(const float* __restrict__ w0, const float* __restrict__ w1,
                            unsigned short* __restrict__ t0, unsigned short* __restrict__ t1) {
  __shared__ float tile[32][33];
  const float* src = blockIdx.z ? w1 : w0;
  unsigned short* dst = blockIdx.z ? t1 : t0;
  int bx = blockIdx.x * 32;
  int by = blockIdx.y * 32;
  int tx = threadIdx.x & 31, ty = threadIdx.x >> 5;
#pragma unroll
  for (int r = 0; r < 32; r += 8)
    tile[ty + r][tx] = src[(by + ty + r) * DM + bx + tx];
  __syncthreads();
#pragma unroll
  for (int r = 0; r < 32; r += 8)
    dst[(bx + ty + r) * DM + by + tx] = f2bf(tile[tx][ty + r]);
}

// ---------------- bf16 MFMA GEMM: C = A @ Wt^T + bias (r13/r14 exact) ----------------
// 256x128 tile, BK=32, 512 thr (8 waves 4Mx2N, per-wave 64x64), dbuf gl_lds
// LDS (48 KiB), ONE __syncthreads drain per K-tile. XOR swizzle
// phys = g ^ ((row>>1)&3); inverse-swizzled global source.
// MODE 0: bf16 out + FUSED chunk-end partial scan in epilogue (r14-verified):
//   chunkL = (1-a)p63 - (1-a)^2 * sum_{r<=62} a^{62-r} p_r ; plast = p63.
//   Wave wm owns one 64-row chunk; its 64-col group = one head -> a uniform.
// MODE 1: fp32 out, row guard (control).
template <int MODE>
__global__ __launch_bounds__(512, 4) void k_gemm(const unsigned short* __restrict__ A16,
                                                 const unsigned short* __restrict__ Bt16,
                                                 const float* __restrict__ bias,
                                                 unsigned short* __restrict__ outb,
                                                 float* __restrict__ outf, int Mvalid,
                                                 const float* __restrict__ slog,
                                                 float* __restrict__ chunkL,
                                                 float* __restrict__ plastg) {
  // buf b at b*12288: A [256r][32k] at +0, B [128r][32k] at +8192 (elems)
  __shared__ unsigned short lds[24576];  // 48 KiB

  const int tid = threadIdx.x;
  const int w = tid >> 6, l = tid & 63;
  const int wm = w >> 1, wn = w & 1;   // 4M x 2N wave grid, per-wave 64x64
  const int lo = l & 15, hi = l >> 4;

  // bijective XCD swizzle (nwg % 8 == 0: 1024 and 1032)
  const int nwg = gridDim.x, orig = blockIdx.x;
  const int cpx = nwg >> 3;
  const int wg = (orig & 7) * cpx + (orig >> 3);
  const int bm = wg >> 3, bn = wg & 7;
  const int blockM = bm * 256;
  const int blockN = bn * 128;

  f32x4 acc[4][4];
#pragma unroll
  for (int m = 0; m < 4; m++)
#pragma unroll
    for (int n = 0; n < 4; n++) acc[m][n] = (f32x4){0.f, 0.f, 0.f, 0.f};

  // staging: lane -> row +(l>>2), phys slot l&3; global source
  // inverse-swizzled: logical granule (l&3) ^ ((l>>3)&3)
  const int sg = (l & 3) ^ ((l >> 3) & 3);
  const unsigned short* pA[2];
#pragma unroll
  for (int c = 0; c < 2; c++)
    pA[c] = A16 + (size_t)(blockM + w * 32 + c * 16 + (l >> 2)) * DM + sg * 8;
  const unsigned short* pB =
      Bt16 + (size_t)(blockN + w * 16 + (l >> 2)) * DM + sg * 8;

  auto stage = [&](int tt, int buf) {
#pragma unroll
    for (int c = 0; c < 2; c++)
      gl_lds16(pA[c] + (size_t)tt * 32, &lds[buf * 12288 + (w * 32 + c * 16) * 32]);
    gl_lds16(pB + (size_t)tt * 32, &lds[buf * 12288 + 8192 + (w * 16) * 32]);
  };

  stage(0, 0);
  __syncthreads();

  for (int t = 0; t < NT; ++t) {
    const int cur = t & 1;
    if (t + 1 < NT) stage(t + 1, cur ^ 1);  // issue next-tile loads FIRST

    bf16x8 aq[4], bq[4];
#pragma unroll
    for (int mf = 0; mf < 4; mf++) {
      const int r = wm * 64 + mf * 16 + lo;
      aq[mf] = *(const bf16x8*)(&lds[cur * 12288 + r * 32 + (hi ^ ((r >> 1) & 3)) * 8]);
    }
#pragma unroll
    for (int nf = 0; nf < 4; nf++) {
      const int r = wn * 64 + nf * 16 + lo;
      bq[nf] = *(const bf16x8*)(&lds[cur * 12288 + 8192 + r * 32 + (hi ^ ((r >> 1) & 3)) * 8]);
    }
#pragma unroll
    for (int mf = 0; mf < 4; mf++)
#pragma unroll
      for (int nf = 0; nf < 4; nf++)
        acc[mf][nf] = __builtin_amdgcn_mfma_f32_16x16x32_bf16(
            bq[nf], aq[mf], acc[mf][nf], 0, 0, 0);

    __syncthreads();  // single drain per K-tile
  }

  // epilogue: swapped mfma(B,A) mapping (r7/r8-verified):
  // row = blockM + wm*64 + mf*16 + lo; col = blockN + wn*64 + nf*16 + hi*4 + j
#pragma unroll
  for (int mf = 0; mf < 4; mf++) {
    const int row = blockM + wm * 64 + mf * 16 + lo;
    if (MODE == 1 && row >= Mvalid) continue;
#pragma unroll
    for (int nf = 0; nf < 4; nf++) {
      const int col = blockN + wn * 64 + nf * 16 + hi * 4;
      const float4 bv = *(const float4*)(bias + col);
      if (MODE == 0) {
        ushort4 o;
        o.x = f2bf(acc[mf][nf][0] + bv.x);
        o.y = f2bf(acc[mf][nf][1] + bv.y);
        o.z = f2bf(acc[mf][nf][2] + bv.z);
        o.w = f2bf(acc[mf][nf][3] + bv.w);
        *(ushort4*)(outb + (size_t)row * DM + col) = o;
      } else {
        float4 o;
        o.x = acc[mf][nf][0] + bv.x;
        o.y = acc[mf][nf][1] + bv.y;
        o.z = acc[mf][nf][2] + bv.z;
        o.w = acc[mf][nf][3] + bv.w;
        *(float4*)(outf + (size_t)row * DM + col) = o;
      }
    }
  }

  if (MODE == 0) {
    // ---- fused chunk-end partial scan (r14-verified) ----
    const float aa = 1.f / (1.f + expf(-slog[(blockN + wn * 64) >> 6]));
    const float one_a = 1.f - aa;
    const float a2v = aa * aa, a4v = a2v * a2v, a8v = a4v * a4v, a16v = a8v * a8v;
    const float w3raw = powf(aa, (float)(14 - lo));  // build UP (underflow-safe)
    float wv[4];
    wv[3] = (lo == 15) ? 0.f : w3raw;
    wv[2] = w3raw * a16v;
    wv[1] = wv[2] * a16v;
    wv[0] = wv[1] * a16v;
    float S[4][4], P63[4][4];
#pragma unroll
    for (int nf = 0; nf < 4; nf++) {
      const int col = blockN + wn * 64 + nf * 16 + hi * 4;
      const float4 bv = *(const float4*)(bias + col);
#pragma unroll
      for (int j = 0; j < 4; j++) {
        const float bj = ((const float*)&bv)[j];
        float s = 0.f, p63 = 0.f;
#pragma unroll
        for (int mf = 0; mf < 4; mf++) {
          const float p = acc[mf][nf][j] + bj;
          s += wv[mf] * p;
          if (mf == 3 && lo == 15) p63 = p;
        }
        S[nf][j] = s;
        P63[nf][j] = p63;
      }
    }
#pragma unroll
    for (int nf = 0; nf < 4; nf++)
#pragma unroll
      for (int j = 0; j < 4; j++)
#pragma unroll
        for (int m = 1; m < 16; m <<= 1) {
          S[nf][j] += __shfl_xor(S[nf][j], m);
          P63[nf][j] += __shfl_xor(P63[nf][j], m);
        }
    const int cglob = (blockM >> 6) + wm;  // = b*NCH + chunk
    if (lo == 0 || lo == 1) {
#pragma unroll
      for (int nf = 0; nf < 4; nf++)
#pragma unroll
        for (int j = 0; j < 4; j++) {
          const int col = blockN + wn * 64 + nf * 16 + hi * 4 + j;
          if (lo == 0)
            chunkL[(size_t)cglob * DM + col] =
                one_a * P63[nf][j] - one_a * one_a * S[nf][j];
          else
            plastg[(size_t)cglob * DM + col] = P63[nf][j];
        }
    }
  }
}

// ---------------- scan final (combine INLINED; 8 ch/thread, bf16x8 I/O) ----------------
// Each block (b,c) redundantly computes its entry state by the serial prefix
// e_{i+1} = aL*e_i + (chunkL[i] - g*plast[i-1]-style correction) over chunks
// 0..c-1 (r14-verified arithmetic), then runs its 64-step chunk scan.
__global__ void k_scan_final(const unsigned short* __restrict__ proj,
                             const float* __restrict__ logit,
                             const float* __restrict__ z0,
                             const float* __restrict__ v0,
                             const float* __restrict__ chunkL,
                             const float* __restrict__ plastg,
                             unsigned short* __restrict__ S) {
  const int b = blockIdx.x >> 6, c = blockIdx.x & 63;
  const int ch0 = threadIdx.x * 8;  // 128 threads x 8 channels (head-uniform)
  const float a = 1.f / (1.f + expf(-logit[ch0 >> 6]));
  const float a2 = a * a, a4 = a2 * a2, a8 = a4 * a4, a16 = a8 * a8, a32 = a16 * a16;
  const float aL = a32 * a32;                                // a^64
  const float g = (1.f - a) * a32 * a16 * a8 * a4 * a2 * a;  // (1-a)*a^63

  // ---- inlined combine: entry state for chunk c
  float s[8], pp8[8];
#pragma unroll
  for (int k = 0; k < 8; k++) {
    s[k] = v0[ch0 + k];
    pp8[k] = z0[ch0 + k];  // p_{-1} of chunk 0
  }
  for (int i = 0; i < c; i++) {
    const float* Lp = chunkL + (size_t)(b * NCH + i) * DM + ch0;
    const float* Pp = plastg + (size_t)(b * NCH + i) * DM + ch0;
#pragma unroll
    for (int k = 0; k < 8; k++) {
      s[k] = aL * s[k] + (Lp[k] - g * pp8[k]);
      pp8[k] = Pp[k];
    }
  }

  // ---- 64-step chunk scan (r13-verified)
  const int t0 = c * CL;
  const unsigned short* p = proj + (size_t)(b * T + t0) * DM + ch0;
  unsigned short* so = S + (size_t)(b * (T + 1) + t0 + 1) * DM + ch0;
  float pprev[8];
  if (t0 == 0) {
#pragma unroll
    for (int k = 0; k < 8; k++) pprev[k] = z0[ch0 + k];
  } else {
    bf16x8 v = *(const bf16x8*)(p - DM);
#pragma unroll
    for (int k = 0; k < 8; k++) pprev[k] = bf2f((unsigned short)v[k]);
  }
  if (c == 0) {
    bf16x8 r;
#pragma unroll
    for (int k = 0; k < 8; k++) r[k] = (short)f2bf(v0[ch0 + k]);
    *(bf16x8*)(S + (size_t)b * (T + 1) * DM + ch0) = r;  // row 0 = v0
  }
  for (int j = 0; j < CL; j++) {
    bf16x8 v = *(const bf16x8*)(p + (size_t)j * DM);
    bf16x8 r;
#pragma unroll
    for (int k = 0; k < 8; k++) {
      float pv = bf2f((unsigned short)v[k]);
      s[k] = a * s[k] + (1.f - a) * (pv - pprev[k]);
      pprev[k] = pv;
      r[k] = (short)f2bf(s[k]);
    }
    *(bf16x8*)(so + (size_t)j * DM) = r;
  }
}

extern "C" void kernel_launch(void* const* d_in, const int* in_sizes, int n_in,
                              void* d_out, int out_size, void* d_ws, size_t ws_size,
                              hipStream_t stream) {
  const float* inputs = (const float*)d_in[0];
  const float* z0     = (const float*)d_in[1];
  const float* W_in   = (const float*)d_in[2];
  const float* b_in   = (const float*)d_in[3];
  const float* W_out  = (const float*)d_in[4];
  const float* b_out  = (const float*)d_in[5];
  const float* slogit = (const float*)d_in[6];
  const float* v0     = (const float*)d_in[7];
  float* out = (float*)d_out;

  char* ws = (char*)d_ws;
  unsigned short* X16   = (unsigned short*)(ws);                 // 67,108,864 B
  unsigned short* P16   = (unsigned short*)(ws + 67108864);      // 67,108,864 B
  unsigned short* S16   = (unsigned short*)(ws + 134217728);     // 67,633,152 B (33024 rows)
  unsigned short* WTin  = (unsigned short*)(ws + 201850880);     // 2,097,152 B
  unsigned short* WTout = (unsigned short*)(ws + 203948032);     // 2,097,152 B
  float* chunkend       = (float*)(ws + 206045184);              // 2,097,152 B
  float* plast          = (float*)(ws + 208142336);              // 2,097,152 B

  // 1. convert inputs to bf16
  k_cvt_x<<<32768, 256, 0, stream>>>((const float4*)inputs, (ushort4*)X16);
  // 2. transpose+convert both weights
  k_transpose<<<dim3(32, 32, 2), 256, 0, stream>>>(W_in, W_out, WTin, WTout);
  // 3. GEMM1 + fused chunk-end partial scan (bf16 out), 128x8 = 1024 wgs
  k_gemm<0><<<dim3((M1 / 256) * 8), 512, 0, stream>>>(X16, WTin, b_in, P16, nullptr, M1,
                                                      slogit, chunkend, plast);
  // 4. scan final with inlined cross-chunk combine
  k_scan_final<<<dim3(BATCH * NCH), 128, 0, stream>>>(P16, slogit, z0, v0,
                                                      chunkend, plast, S16);
  // (pad rows of S16 are unwritten poison: finite bf16, outputs row-guarded)
  // 5. GEMM2 (control): out = S @ W_out + b_out (fp32, 32776 valid of 33024), 129x8 wgs
  k_gemm<1><<<dim3((M2P / 256) * 8), 512, 0, stream>>>(S16, WTout, b_out, nullptr, out, M2,
                                                       nullptr, nullptr, nullptr);
}

// Round 19
// 275.049 us; speedup vs baseline: 1.0204x; 1.0204x over previous
//
#include <hip/hip_runtime.h>
#include <hip/hip_bf16.h>
#include <stdint.h>

#define DEV static __device__ __forceinline__

typedef __attribute__((ext_vector_type(8))) short bf16x8;
typedef __attribute__((ext_vector_type(4))) float f32x4;
typedef unsigned int u32;

static constexpr int T = 4096;
static constexpr int BATCH = 8;
static constexpr int DM = 1024;            // d_model
static constexpr int M1 = BATCH * T;       // 32768 rows into GEMM1
static constexpr int M2 = BATCH * (T + 1); // 32776 rows into GEMM2
static constexpr int M2P = 129 * 256;      // 33024 padded rows for S (256-row tiles)
static constexpr int NCH = 64;
static constexpr int CL = T / NCH;
static constexpr int NT = 32;              // K tiles (BK=32, K=1024)

DEV unsigned short f2bf(float f) {
  union { float f; unsigned u; } v; v.f = f;
  unsigned u = v.u;
  return (unsigned short)((u + 0x7fffu + ((u >> 16) & 1u)) >> 16);
}
DEV float bf2f(unsigned short s) {
  union { unsigned u; float f; } v; v.u = ((unsigned)s) << 16;
  return v.f;
}

// async global->LDS, 16B per lane. lds dest wave-uniform; g per-lane.
DEV void gl_lds16(const unsigned short* g, unsigned short* lds) {
  __builtin_amdgcn_global_load_lds(
      (const __attribute__((address_space(1))) u32*)g,
      (__attribute__((address_space(3))) u32*)lds,
      16, 0, 0);
}

// -------- merged prep: weight transpose+cvt (blocks 0..2047) + input cvt --------
__global__ void k_prep(const float4* __restrict__ x, ushort4* __restrict__ o,
                       const float* __restrict__ w0, const float* __restrict__ w1,
                       unsigned short* __restrict__ t0, unsigned short* __restrict__ t1) {
  __shared__ float tile[32][33];
  const int bid = blockIdx.x;
  if (bid < 2048) {
    // transpose+convert Wt[n][k] = W[k][n]; z = bid>>10, 32x32 tile grid
    const int z = bid >> 10;
    const int by = ((bid >> 5) & 31) * 32;  // k
    const int bx = (bid & 31) * 32;         // n
    const float* src = z ? w1 : w0;
    unsigned short* dst = z ? t1 : t0;
    const int tx = threadIdx.x & 31, ty = threadIdx.x >> 5;
#pragma unroll
    for (int r = 0; r < 32; r += 8)
      tile[ty + r][tx] = src[(by + ty + r) * DM + bx + tx];
    __syncthreads();
#pragma unroll
    for (int r = 0; r < 32; r += 8)
      dst[(bx + ty + r) * DM + by + tx] = f2bf(tile[tx][ty + r]);
  } else {
    const int i = (bid - 2048) * 256 + threadIdx.x;  // 8388608 float4s
    float4 v = x[i];
    ushort4 r;
    r.x = f2bf(v.x); r.y = f2bf(v.y); r.z = f2bf(v.z); r.w = f2bf(v.w);
    o[i] = r;
  }
}

// ---------------- bf16 MFMA GEMM: C = A @ Wt^T + bias (r17 exact) ----------------
// 256x128 tile, BK=32, single-drain 2-phase skeleton, 4 waves (2M x 2N),
// per-wave 128x64 output (m=8 x n=4 frags). LDS 48 KiB dbuf; gl_lds staging,
// XOR swizzle phys = g ^ ((row>>1)&3), inverse-swizzled global source.
// MODE 0: bf16 out. MODE 1: fp32 out, row guard.
template <int MODE>
__global__ __launch_bounds__(256, 2) void k_gemm(const unsigned short* __restrict__ A16,
                                                 const unsigned short* __restrict__ Bt16,
                                                 const float* __restrict__ bias,
                                                 unsigned short* __restrict__ outb,
                                                 float* __restrict__ outf, int Mvalid) {
  // buf b at b*12288 elems: A [256r][32k] at +0, B [128r][32k] at +8192
  __shared__ unsigned short lds[24576];  // 48 KiB

  const int tid = threadIdx.x;
  const int w = tid >> 6, l = tid & 63;
  const int wm = w >> 1, wn = w & 1;   // 2M x 2N wave grid, per-wave 128x64
  const int lo = l & 15, hi = l >> 4;

  // bijective XCD swizzle (nwg % 8 == 0: 1024 and 1032)
  const int nwg = gridDim.x, orig = blockIdx.x;
  const int cpx = nwg >> 3;
  const int wg = (orig & 7) * cpx + (orig >> 3);
  const int bm = wg >> 3, bn = wg & 7;
  const int blockM = bm * 256;
  const int blockN = bn * 128;

  f32x4 acc[8][4];
#pragma unroll
  for (int m = 0; m < 8; m++)
#pragma unroll
    for (int n = 0; n < 4; n++) acc[m][n] = (f32x4){0.f, 0.f, 0.f, 0.f};

  // staging: 6 gl_lds/thread. Wave w: A rows [w*64, w*64+64) as 4 chunks of
  // 16 rows; B rows [w*32, w*32+32) as 2 chunks. lane -> row +(l>>2), phys
  // slot l&3; global source inverse-swizzled: granule (l&3)^((l>>3)&3).
  const int sg = (l & 3) ^ ((l >> 3) & 3);
  const unsigned short* pA[4];
#pragma unroll
  for (int c = 0; c < 4; c++)
    pA[c] = A16 + (size_t)(blockM + w * 64 + c * 16 + (l >> 2)) * DM + sg * 8;
  const unsigned short* pB[2];
#pragma unroll
  for (int c = 0; c < 2; c++)
    pB[c] = Bt16 + (size_t)(blockN + w * 32 + c * 16 + (l >> 2)) * DM + sg * 8;

  auto stage = [&](int tt, int buf) {
#pragma unroll
    for (int c = 0; c < 4; c++)
      gl_lds16(pA[c] + (size_t)tt * 32, &lds[buf * 12288 + (w * 64 + c * 16) * 32]);
#pragma unroll
    for (int c = 0; c < 2; c++)
      gl_lds16(pB[c] + (size_t)tt * 32, &lds[buf * 12288 + 8192 + (w * 32 + c * 16) * 32]);
  };

  stage(0, 0);
  __syncthreads();

  for (int t = 0; t < NT; ++t) {
    const int cur = t & 1;
    if (t + 1 < NT) stage(t + 1, cur ^ 1);  // issue next-tile loads FIRST

    bf16x8 aq[8], bq[4];
#pragma unroll
    for (int mf = 0; mf < 8; mf++) {
      const int r = wm * 128 + mf * 16 + lo;
      aq[mf] = *(const bf16x8*)(&lds[cur * 12288 + r * 32 + (hi ^ ((r >> 1) & 3)) * 8]);
    }
#pragma unroll
    for (int nf = 0; nf < 4; nf++) {
      const int r = wn * 64 + nf * 16 + lo;
      bq[nf] = *(const bf16x8*)(&lds[cur * 12288 + 8192 + r * 32 + (hi ^ ((r >> 1) & 3)) * 8]);
    }
#pragma unroll
    for (int mf = 0; mf < 8; mf++)
#pragma unroll
      for (int nf = 0; nf < 4; nf++)
        acc[mf][nf] = __builtin_amdgcn_mfma_f32_16x16x32_bf16(
            bq[nf], aq[mf], acc[mf][nf], 0, 0, 0);

    __syncthreads();  // single drain per K-tile
  }

  // epilogue: swapped mfma(B,A) mapping (r7/r8-verified):
  // row = blockM + wm*128 + mf*16 + lo; col = blockN + wn*64 + nf*16 + hi*4 + j
#pragma unroll
  for (int mf = 0; mf < 8; mf++) {
    const int row = blockM + wm * 128 + mf * 16 + lo;
    if (MODE == 1 && row >= Mvalid) continue;
#pragma unroll
    for (int nf = 0; nf < 4; nf++) {
      const int col = blockN + wn * 64 + nf * 16 + hi * 4;
      const float4 bv = *(const float4*)(bias + col);
      if (MODE == 0) {
        ushort4 o;
        o.x = f2bf(acc[mf][nf][0] + bv.x);
        o.y = f2bf(acc[mf][nf][1] + bv.y);
        o.z = f2bf(acc[mf][nf][2] + bv.z);
        o.w = f2bf(acc[mf][nf][3] + bv.w);
        *(ushort4*)(outb + (size_t)row * DM + col) = o;
      } else {
        float4 o;
        o.x = acc[mf][nf][0] + bv.x;
        o.y = acc[mf][nf][1] + bv.y;
        o.z = acc[mf][nf][2] + bv.z;
        o.w = acc[mf][nf][3] + bv.w;
        *(float4*)(outf + (size_t)row * DM + col) = o;
      }
    }
  }
}

// ---------------- scan phase A (vectorized: 8 ch/thread) ----------------
__global__ void k_scan_partial(const unsigned short* __restrict__ proj,
                               const float* __restrict__ logit,
                               const float* __restrict__ z0,
                               float* __restrict__ chunkend) {
  const int b = blockIdx.x >> 6, c = blockIdx.x & 63;
  const int ch0 = threadIdx.x * 8;
  const float a = 1.f / (1.f + expf(-logit[ch0 >> 6]));
  const int t0 = c * CL;
  const unsigned short* p = proj + (size_t)(b * T + t0) * DM + ch0;
  float pprev[8], s[8];
  if (t0 == 0) {
#pragma unroll
    for (int k = 0; k < 8; k++) pprev[k] = z0[ch0 + k];
  } else {
    bf16x8 v = *(const bf16x8*)(p - DM);
#pragma unroll
    for (int k = 0; k < 8; k++) pprev[k] = bf2f((unsigned short)v[k]);
  }
#pragma unroll
  for (int k = 0; k < 8; k++) s[k] = 0.f;
  for (int j = 0; j < CL; j++) {
    bf16x8 v = *(const bf16x8*)(p + (size_t)j * DM);
#pragma unroll
    for (int k = 0; k < 8; k++) {
      float pv = bf2f((unsigned short)v[k]);
      s[k] = a * s[k] + (1.f - a) * (pv - pprev[k]);
      pprev[k] = pv;
    }
  }
  float* o = chunkend + (size_t)(b * NCH + c) * DM + ch0;
#pragma unroll
  for (int k = 0; k < 4; k++) ((float2*)o)[k] = make_float2(s[2 * k], s[2 * k + 1]);
}

// ---------------- scan phase B (vectorized: 4 ch/thread) ----------------
__global__ void k_scan_combine(const float* __restrict__ chunkend,
                               const float* __restrict__ logit,
                               const float* __restrict__ v0,
                               float* __restrict__ enter) {
  const int b = blockIdx.x;
  const int ch0 = threadIdx.x * 4;
  const float a = 1.f / (1.f + expf(-logit[ch0 >> 6]));
  const float a2 = a * a, a4 = a2 * a2, a8 = a4 * a4, a16 = a8 * a8, a32 = a16 * a16;
  const float aL = a32 * a32;  // a^64
  float4 e = *(const float4*)(v0 + ch0);
  *(float4*)(enter + (size_t)(b * NCH) * DM + ch0) = e;
  for (int c = 1; c < NCH; c++) {
    const float4 ce = *(const float4*)(chunkend + (size_t)(b * NCH + c - 1) * DM + ch0);
    e.x = aL * e.x + ce.x;
    e.y = aL * e.y + ce.y;
    e.z = aL * e.z + ce.z;
    e.w = aL * e.w + ce.w;
    *(float4*)(enter + (size_t)(b * NCH + c) * DM + ch0) = e;
  }
}

// ---------------- scan phase C (vectorized: 8 ch/thread) ----------------
__global__ void k_scan_final(const unsigned short* __restrict__ proj,
                             const float* __restrict__ logit,
                             const float* __restrict__ z0,
                             const float* __restrict__ v0,
                             const float* __restrict__ enter,
                             unsigned short* __restrict__ S) {
  const int b = blockIdx.x >> 6, c = blockIdx.x & 63;
  const int ch0 = threadIdx.x * 8;
  const float a = 1.f / (1.f + expf(-logit[ch0 >> 6]));
  const int t0 = c * CL;
  const unsigned short* p = proj + (size_t)(b * T + t0) * DM + ch0;
  unsigned short* so = S + (size_t)(b * (T + 1) + t0 + 1) * DM + ch0;
  float pprev[8], s[8];
  if (t0 == 0) {
#pragma unroll
    for (int k = 0; k < 8; k++) pprev[k] = z0[ch0 + k];
  } else {
    bf16x8 v = *(const bf16x8*)(p - DM);
#pragma unroll
    for (int k = 0; k < 8; k++) pprev[k] = bf2f((unsigned short)v[k]);
  }
  {
    const float* e = enter + (size_t)(b * NCH + c) * DM + ch0;
#pragma unroll
    for (int k = 0; k < 8; k++) s[k] = e[k];
  }
  if (c == 0) {
    bf16x8 r;
#pragma unroll
    for (int k = 0; k < 8; k++) r[k] = (short)f2bf(v0[ch0 + k]);
    *(bf16x8*)(S + (size_t)b * (T + 1) * DM + ch0) = r;  // row 0 = v0
  }
  for (int j = 0; j < CL; j++) {
    bf16x8 v = *(const bf16x8*)(p + (size_t)j * DM);
    bf16x8 r;
#pragma unroll
    for (int k = 0; k < 8; k++) {
      float pv = bf2f((unsigned short)v[k]);
      s[k] = a * s[k] + (1.f - a) * (pv - pprev[k]);
      pprev[k] = pv;
      r[k] = (short)f2bf(s[k]);
    }
    *(bf16x8*)(so + (size_t)j * DM) = r;
  }
}

extern "C" void kernel_launch(void* const* d_in, const int* in_sizes, int n_in,
                              void* d_out, int out_size, void* d_ws, size_t ws_size,
                              hipStream_t stream) {
  const float* inputs = (const float*)d_in[0];
  const float* z0     = (const float*)d_in[1];
  const float* W_in   = (const float*)d_in[2];
  const float* b_in   = (const float*)d_in[3];
  const float* W_out  = (const float*)d_in[4];
  const float* b_out  = (const float*)d_in[5];
  const float* slogit = (const float*)d_in[6];
  const float* v0     = (const float*)d_in[7];
  float* out = (float*)d_out;

  char* ws = (char*)d_ws;
  unsigned short* X16   = (unsigned short*)(ws);                 // 67,108,864 B
  unsigned short* P16   = (unsigned short*)(ws + 67108864);      // 67,108,864 B
  unsigned short* S16   = (unsigned short*)(ws + 134217728);     // 67,633,152 B (33024 rows)
  unsigned short* WTin  = (unsigned short*)(ws + 201850880);     // 2,097,152 B
  unsigned short* WTout = (unsigned short*)(ws + 203948032);     // 2,097,152 B
  float* chunkend       = (float*)(ws + 206045184);              // 2,097,152 B
  float* enter          = (float*)(ws + 208142336);              // 2,097,152 B

  // 1. merged prep: weight transpose+cvt (2048 blocks) + input cvt (32768)
  k_prep<<<dim3(2048 + 32768), 256, 0, stream>>>((const float4*)inputs, (ushort4*)X16,
                                                 W_in, W_out, WTin, WTout);
  // 2. GEMM1: proj = inputs @ W_in + b_in (bf16 out), 128x8 = 1024 wgs
  k_gemm<0><<<dim3((M1 / 256) * 8), 256, 0, stream>>>(X16, WTin, b_in, P16, nullptr, M1);
  // 3. scan: temporal diff + exponential smoothing (vectorized)
  k_scan_partial<<<dim3(BATCH * NCH), 128, 0, stream>>>(P16, slogit, z0, chunkend);
  k_scan_combine<<<dim3(BATCH), 256, 0, stream>>>(chunkend, slogit, v0, enter);
  k_scan_final<<<dim3(BATCH * NCH), 128, 0, stream>>>(P16, slogit, z0, v0, enter, S16);
  // (pad rows of S16 are unwritten poison: finite bf16, outputs row-guarded)
  // 4. GEMM2: out = S @ W_out + b_out (fp32, 32776 valid of 33024), 129x8 = 1032 wgs
  k_gemm<1><<<dim3((M2P / 256) * 8), 256, 0, stream>>>(S16, WTout, b_out, nullptr, out, M2);
}